// Round 11
// baseline (265.790 us; speedup 1.0000x reference)
//
#include <hip/hip_runtime.h>
#include <hip/hip_bf16.h>

typedef __attribute__((ext_vector_type(4))) float f32x4;
typedef __attribute__((ext_vector_type(8))) short s16x8;

constexpr int NN   = 8192;
constexpr int KIN  = 512;
constexpr int KOUT = 128;

constexpr int RB  = 16;           // rows per block
constexpr int SGO = 512;          // cols per outer stage
constexpr int NSO = NN / SGO;     // 16 outer stages
constexpr int NKI = SGO / 32;     // 16 inner k-steps

__device__ __forceinline__ ushort f2bf(float x) {
    union { float f; unsigned u; } v; v.f = x;
    unsigned r = (v.u + 0x7fffu + ((v.u >> 16) & 1u)) >> 16;
    return (ushort)r;
}

// ---------------- Kernel A: h = input @ W ; hT(bf16), s, t ----------------
__global__ __launch_bounds__(256) void kA(const float* __restrict__ inp,
                                          const float* __restrict__ W,
                                          const float* __restrict__ a_s,
                                          const float* __restrict__ a_n,
                                          ushort* __restrict__ hT,
                                          float* __restrict__ s_out,
                                          float* __restrict__ t_out) {
    __shared__ float smem[16 * 512];
    const int t = threadIdx.x;
    const int rbase = blockIdx.x * 16;

#pragma unroll
    for (int it = 0; it < 8; ++it) {
        int idx = it * 256 + t;
        int r = idx >> 7;
        int c4 = (idx & 127) << 2;
        *(f32x4*)(&smem[r * 512 + c4]) =
            *(const f32x4*)(inp + (size_t)(rbase + r) * KIN + c4);
    }
    __syncthreads();

    const int c0 = (t & 31) * 4;
    const int rg = (t >> 5) * 2;
    float acc[2][4] = {};
#pragma unroll 4
    for (int k = 0; k < KIN; ++k) {
        f32x4 w4 = *(const f32x4*)(W + (size_t)k * KOUT + c0);
        float a0 = smem[(rg + 0) * 512 + k];
        float a1 = smem[(rg + 1) * 512 + k];
#pragma unroll
        for (int cc = 0; cc < 4; ++cc) {
            acc[0][cc] += a0 * w4[cc];
            acc[1][cc] += a1 * w4[cc];
        }
    }
    __syncthreads();

    float* h_lds = smem;                        // [16][128]
#pragma unroll
    for (int rr = 0; rr < 2; ++rr) {
        f32x4 v = {acc[rr][0], acc[rr][1], acc[rr][2], acc[rr][3]};
        *(f32x4*)(&h_lds[(rg + rr) * 128 + c0]) = v;
    }
    __syncthreads();

    {
        const int col = t >> 1;
        const int r0 = (t & 1) * 8;
        ushort tmp[8];
#pragma unroll
        for (int rr = 0; rr < 8; ++rr) tmp[rr] = f2bf(h_lds[(r0 + rr) * 128 + col]);
        *(f32x4*)(hT + (size_t)col * NN + rbase + r0) = *(f32x4*)&tmp[0];
    }

    {
        const int w = t >> 6, lane = t & 63;
        float as1 = a_s[lane], as2 = a_s[64 + lane];
        float an1 = a_n[lane], an2 = a_n[64 + lane];
#pragma unroll
        for (int rr = 0; rr < 4; ++rr) {
            int row = w * 4 + rr;
            float h1 = h_lds[row * 128 + lane];
            float h2 = h_lds[row * 128 + 64 + lane];
            float ps = h1 * as1 + h2 * as2;
            float pt = h1 * an1 + h2 * an2;
#pragma unroll
            for (int off = 32; off; off >>= 1) {
                ps += __shfl_xor(ps, off);
                pt += __shfl_xor(pt, off);
            }
            if (lane == 0) {
                s_out[rbase + row] = ps;
                t_out[rbase + row] = pt;
            }
        }
    }
}

// ---------------- Kernel F: fully fused, lane-consecutive streaming ----------------
// 512 blocks, block = 16 rows x all 8192 cols. 4 waves; wave w: producer rows w*4..+3,
// consumer output cols [w*32, w*32+32).
// Outer stage (512 cols): stream M/adj as 1KB-contiguous loads -> exp in-lane ->
// bf16 pack -> swizzled P_lds (transpose) -> 16 MFMA k-steps; B-frags direct from
// L2-resident hT. Epilogue: in-block l, divide, ELU, final store. No kC.
__global__ __launch_bounds__(256, 2) void kF(const float* __restrict__ Mmat,
                                             const float* __restrict__ adjm,
                                             const ushort* __restrict__ hT,
                                             const float* __restrict__ s_in,
                                             const float* __restrict__ t_in,
                                             float* __restrict__ out) {
    __shared__ __align__(16) char Plds[2][16 * 1024];   // dbuf: [16 rows][512 bf16], swizzled
    __shared__ float l_lds[16];

    const int tid = threadIdx.x;
    const int w = tid >> 6;
    const int l = tid & 63;
    const int lrow = l & 15;
    const int kgrp = l >> 4;
    const int row0 = blockIdx.x * RB;
    const int PH = (int)((blockIdx.x * 5u) & (unsigned)(NSO - 1));   // stage phase spread

    float sr[4];
#pragma unroll
    for (int rr = 0; rr < 4; ++rr) sr[rr] = s_in[row0 + w * 4 + rr];

    // producer bases: instr q -> row w*4+(q&3), half h=q>>2, floats l*4..+3 (1KB/instr contiguous)
    const float* Mb = Mmat + (size_t)(row0 + w * 4) * NN + l * 4;
    const float* Ab = adjm + (size_t)(row0 + w * 4) * NN + l * 4;
    const float* tb = t_in + l * 4;

    // B-frag bases: lane reads hT[w*32 + (cc*16) + lrow][j + kgrp*8 .. +7]
    const ushort* hB0 = hT + (size_t)(w * 32 + lrow) * NN + kgrp * 8;
    const ushort* hB1 = hB0 + (size_t)16 * NN;

    f32x4 acc0 = {0.f, 0.f, 0.f, 0.f}, acc1 = {0.f, 0.f, 0.f, 0.f};
    float lsum[4] = {0.f, 0.f, 0.f, 0.f};

    f32x4 Mr[8], Ar[8], Tr[2];

#define LDSTREAM(n)                                                              \
    {                                                                            \
        _Pragma("unroll") for (int q = 0; q < 8; ++q) {                          \
            Mr[q] = *(const f32x4*)(Mb + (size_t)(q & 3) * NN + (n) * SGO + (q >> 2) * 256); \
            Ar[q] = *(const f32x4*)(Ab + (size_t)(q & 3) * NN + (n) * SGO + (q >> 2) * 256); \
        }                                                                        \
        Tr[0] = *(const f32x4*)(tb + (n) * SGO);                                 \
        Tr[1] = *(const f32x4*)(tb + (n) * SGO + 256);                           \
    }

#define EXPW(n)                                                                  \
    {                                                                            \
        char* pb = Plds[(n) & 1];                                                \
        _Pragma("unroll") for (int q = 0; q < 8; ++q) {                          \
            const int rr = q & 3, h = q >> 2;                                    \
            const int row = w * 4 + rr;                                          \
            float pv[4];                                                         \
            _Pragma("unroll") for (int e = 0; e < 4; ++e) {                      \
                float x = (sr[rr] + Tr[h][e]) * Mr[q][e];                        \
                x = fmaxf(x, 0.2f * x);                                          \
                float p = __expf(x) * Ar[q][e];     /* adj is exactly 0/1 */     \
                lsum[rr] += p;                                                   \
                pv[e] = p;                                                       \
            }                                                                    \
            unsigned b0 = (unsigned)f2bf(pv[0]) | ((unsigned)f2bf(pv[1]) << 16); \
            unsigned b1 = (unsigned)f2bf(pv[2]) | ((unsigned)f2bf(pv[3]) << 16); \
            int off = (h * 512 + l * 8) ^ ((row & 7) << 4);                      \
            *(uint2*)(pb + row * 1024 + off) = make_uint2(b0, b1);               \
        }                                                                        \
    }

#define INNER_K(n, k)                                                            \
    {                                                                            \
        const char* pb = Plds[(n) & 1];                                          \
        s16x8 af = *(const s16x8*)(pb + lrow * 1024 +                            \
                                   (((k) * 64 + kgrp * 16) ^ ((lrow & 7) << 4)));\
        s16x8 b0 = *(const s16x8*)(hB0 + (size_t)(n) * SGO + (k) * 32);          \
        s16x8 b1 = *(const s16x8*)(hB1 + (size_t)(n) * SGO + (k) * 32);          \
        acc0 = __builtin_amdgcn_mfma_f32_16x16x32_bf16(af, b0, acc0, 0, 0, 0);   \
        acc1 = __builtin_amdgcn_mfma_f32_16x16x32_bf16(af, b1, acc1, 0, 0, 0);   \
    }

    // prologue: stage PH data + P(PH) into buf[PH&1]; then stage PH+1 data in regs
    LDSTREAM(PH)
    EXPW(PH)
    LDSTREAM((PH + 1) & (NSO - 1))

#pragma unroll 1
    for (int s = 0; s < NSO; ++s) {
        const int n = (s + PH) & (NSO - 1);            // physical stage
        asm volatile("s_waitcnt lgkmcnt(0)" ::: "memory");
        __builtin_amdgcn_s_barrier();                  // bar1: prev INNER done reading buf[(n+1)&1]
        if (s + 1 < NSO) { EXPW(((n + 1) & (NSO - 1))) }   // consumes reg set (stage n+1 data)
        asm volatile("s_waitcnt lgkmcnt(0)" ::: "memory");
        __builtin_amdgcn_s_barrier();                  // bar2: P(n) fully written (last stage)
        // inner half 1
#pragma unroll
        for (int k = 0; k < 8; ++k) INNER_K(n, k)
        asm volatile("" ::: "memory");
        if (s + 2 < NSO) { LDSTREAM(((n + 2) & (NSO - 1))) }   // mid-stage issue, pinned
        asm volatile("" ::: "memory");
        // inner half 2
#pragma unroll
        for (int k = 8; k < 16; ++k) INNER_K(n, k)
    }
#undef LDSTREAM
#undef EXPW
#undef INNER_K

    // ---- epilogue: denominators, divide, ELU, final store ----
#pragma unroll
    for (int rr = 0; rr < 4; ++rr) {
        float v = lsum[rr];
#pragma unroll
        for (int off = 32; off; off >>= 1) v += __shfl_xor(v, off);
        if (l == 0) l_lds[w * 4 + rr] = v;
    }
    asm volatile("s_waitcnt lgkmcnt(0)" ::: "memory");
    __builtin_amdgcn_s_barrier();

#pragma unroll
    for (int r = 0; r < 4; ++r) {
        const int rl = kgrp * 4 + r;                   // D layout: row=(lane>>4)*4+reg
        const float inv = 1.0f / l_lds[rl];
        float v0 = acc0[r] * inv;
        float v1 = acc1[r] * inv;
        v0 = v0 > 0.f ? v0 : (__expf(v0) - 1.f);
        v1 = v1 > 0.f ? v1 : (__expf(v1) - 1.f);
        out[(size_t)(row0 + rl) * KOUT + w * 32 + lrow] = v0;
        out[(size_t)(row0 + rl) * KOUT + w * 32 + 16 + lrow] = v1;
    }
}

extern "C" void kernel_launch(void* const* d_in, const int* in_sizes, int n_in,
                              void* d_out, int out_size, void* d_ws, size_t ws_size,
                              hipStream_t stream) {
    const float* inp = (const float*)d_in[0];
    const float* adj = (const float*)d_in[1];
    const float* Mm  = (const float*)d_in[2];
    const float* W   = (const float*)d_in[3];
    const float* a_s = (const float*)d_in[4];
    const float* a_n = (const float*)d_in[5];
    float* out = (float*)d_out;

    char* ws = (char*)d_ws;
    ushort* hT    = (ushort*)(ws + 0);              //  2 MB  [128][8192] bf16
    float*  s_buf = (float*)(ws + 2097152);         //  32 KB
    float*  t_buf = (float*)(ws + 2129920);         //  32 KB

    hipLaunchKernelGGL(kA, dim3(512), dim3(256), 0, stream, inp, W, a_s, a_n, hT, s_buf, t_buf);
    hipLaunchKernelGGL(kF, dim3(NN / RB), dim3(256), 0, stream, Mm, adj, hT, s_buf, t_buf, out);
}

// Round 12
// 177.590 us; speedup vs baseline: 1.4966x; 1.4966x over previous
//
#include <hip/hip_runtime.h>
#include <hip/hip_bf16.h>

typedef __attribute__((ext_vector_type(4))) float f32x4;
typedef __attribute__((ext_vector_type(8))) short s16x8;

constexpr int NN   = 8192;
constexpr int KIN  = 512;
constexpr int KOUT = 128;

constexpr int RBK  = 128;             // rows per block
constexpr int JC   = 4;               // column chunks
constexpr int JLEN = NN / JC;         // 2048
constexpr int SGO  = 128;             // cols per stage
constexpr int NS   = JLEN / SGO;      // 16 stages
constexpr int SLAB = 128 * 256;       // 32 KB hT slab (128 feat-rows x 128 cols bf16)

__device__ __forceinline__ ushort f2bf(float x) {
    union { float f; unsigned u; } v; v.f = x;
    unsigned r = (v.u + 0x7fffu + ((v.u >> 16) & 1u)) >> 16;
    return (ushort)r;
}

__device__ __forceinline__ void gload_lds16(const void* g, void* l) {
    __builtin_amdgcn_global_load_lds((const __attribute__((address_space(1))) void*)g,
                                     (__attribute__((address_space(3))) void*)l, 16, 0, 0);
}

// ---------------- Kernel A: h = input @ W ; hT(bf16), s, t ----------------
__global__ __launch_bounds__(256) void kA(const float* __restrict__ inp,
                                          const float* __restrict__ W,
                                          const float* __restrict__ a_s,
                                          const float* __restrict__ a_n,
                                          ushort* __restrict__ hT,
                                          float* __restrict__ s_out,
                                          float* __restrict__ t_out) {
    __shared__ float smem[16 * 512];
    const int t = threadIdx.x;
    const int rbase = blockIdx.x * 16;

#pragma unroll
    for (int it = 0; it < 8; ++it) {
        int idx = it * 256 + t;
        int r = idx >> 7;
        int c4 = (idx & 127) << 2;
        *(f32x4*)(&smem[r * 512 + c4]) =
            *(const f32x4*)(inp + (size_t)(rbase + r) * KIN + c4);
    }
    __syncthreads();

    const int c0 = (t & 31) * 4;
    const int rg = (t >> 5) * 2;
    float acc[2][4] = {};
#pragma unroll 4
    for (int k = 0; k < KIN; ++k) {
        f32x4 w4 = *(const f32x4*)(W + (size_t)k * KOUT + c0);
        float a0 = smem[(rg + 0) * 512 + k];
        float a1 = smem[(rg + 1) * 512 + k];
#pragma unroll
        for (int cc = 0; cc < 4; ++cc) {
            acc[0][cc] += a0 * w4[cc];
            acc[1][cc] += a1 * w4[cc];
        }
    }
    __syncthreads();

    float* h_lds = smem;                        // [16][128]
#pragma unroll
    for (int rr = 0; rr < 2; ++rr) {
        f32x4 v = {acc[rr][0], acc[rr][1], acc[rr][2], acc[rr][3]};
        *(f32x4*)(&h_lds[(rg + rr) * 128 + c0]) = v;
    }
    __syncthreads();

    {
        const int col = t >> 1;
        const int r0 = (t & 1) * 8;
        ushort tmp[8];
#pragma unroll
        for (int rr = 0; rr < 8; ++rr) tmp[rr] = f2bf(h_lds[(r0 + rr) * 128 + col]);
        *(f32x4*)(hT + (size_t)col * NN + rbase + r0) = *(f32x4*)&tmp[0];
    }

    {
        const int w = t >> 6, lane = t & 63;
        float as1 = a_s[lane], as2 = a_s[64 + lane];
        float an1 = a_n[lane], an2 = a_n[64 + lane];
#pragma unroll
        for (int rr = 0; rr < 4; ++rr) {
            int row = w * 4 + rr;
            float h1 = h_lds[row * 128 + lane];
            float h2 = h_lds[row * 128 + 64 + lane];
            float ps = h1 * as1 + h2 * as2;
            float pt = h1 * an1 + h2 * an2;
#pragma unroll
            for (int off = 32; off; off >>= 1) {
                ps += __shfl_xor(ps, off);
                pt += __shfl_xor(pt, off);
            }
            if (lane == 0) {
                s_out[rbase + row] = ps;
                t_out[rbase + row] = pt;
            }
        }
    }
}

// ---------------- Kernel G: 128-row blocks, 1/CU, byte-minimal + big stages ----------------
// grid 256: rb = bid>>2 (128 rows), jc = bid&3 (2048 cols). 8 waves (512 thr), wave w rows w*16..+15.
// Per stage (128 cols): hT slab 32KB -> LDS dbuf via 4 gload_lds/wave at stage start;
// M/adj/t fragment-layout register groups, 4 static slots, distance 4 k-steps.
// Exact issue order per stage: [DMA(4)] [k0..k3: wait vmcnt(22), compute, LD_G next-stage]
// -> uniform vmcnt(22) = 3 groups(18) + DMA(4). Stage end: vmcnt(24) retires next DMA, barrier.
__global__ __launch_bounds__(512, 2) void kG(const float* __restrict__ Mmat,
                                             const float* __restrict__ adjm,
                                             const ushort* __restrict__ hT,
                                             const float* __restrict__ s_in,
                                             const float* __restrict__ t_in,
                                             float* __restrict__ o_part,
                                             float* __restrict__ l_part) {
    __shared__ __align__(16) char slab[2][SLAB];

    const int tid = threadIdx.x;
    const int w = tid >> 6;              // 0..7
    const int l = tid & 63;
    const int lrow = l & 15;             // MFMA A-row this lane owns
    const int kgrp = l >> 4;             // MFMA k-group (8 cols each)
    const int rb = blockIdx.x >> 2;
    const int jc = blockIdx.x & 3;
    const int j0 = jc * JLEN;
    const int row0 = rb * RBK;
    const int i = row0 + w * 16 + lrow;
    const int PH = rb & (NS - 1);        // per-row-block stage phase spread

    const float si = s_in[i];

    // fragment-layout stream sources (lane = consumer, zero redistribution)
    const float* Mp = Mmat + (size_t)i * NN + j0 + kgrp * 8;
    const float* Ap = adjm + (size_t)i * NN + j0 + kgrp * 8;
    const float* tp = t_in + j0 + kgrp * 8;

    // hT DMA sources: instr q stages feat-rows w*16+q*4..+3 x 128 cols (1KB, linear LDS dst).
    // Pre-swizzled source col so LDS read (cb ^ ((lrow&7)<<4)) hits original data (rule #21).
    const ushort* hq[4];
#pragma unroll
    for (int q = 0; q < 4; ++q) {
        int r = w * 16 + q * 4 + (l >> 4);                // lane's staged feat-row
        int sc = ((l & 15) ^ (r & 7)) * 8;                // swizzled col (8 ushorts = 16B)
        hq[q] = hT + (size_t)r * NN + j0 + sc;
    }

    f32x4 acc[8];
#pragma unroll
    for (int ct = 0; ct < 8; ++ct) acc[ct] = (f32x4){0.f, 0.f, 0.f, 0.f};
    float lsum = 0.f;

    // stream register groups, static slots 0..3
    f32x4 gm0[4], gm1[4], ga0[4], ga1[4], gt0[4], gt1[4];

#define DMA_HT(P, SL)                                                            \
    _Pragma("unroll") for (int q = 0; q < 4; ++q)                                \
        gload_lds16(hq[q] + (P) * SGO, &slab[SL][0] + (w * 16 + q * 4) * 256);

#define LD_G(K, P)                                                               \
    {                                                                            \
        const float* mp_ = Mp + (P) * SGO + (K) * 32;                            \
        gm0[K] = *(const f32x4*)mp_;                                             \
        gm1[K] = *(const f32x4*)(mp_ + 4);                                       \
        const float* ap_ = Ap + (P) * SGO + (K) * 32;                            \
        ga0[K] = *(const f32x4*)ap_;                                             \
        ga1[K] = *(const f32x4*)(ap_ + 4);                                       \
        const float* tp_ = tp + (P) * SGO + (K) * 32;                            \
        gt0[K] = *(const f32x4*)tp_;                                             \
        gt1[K] = *(const f32x4*)(tp_ + 4);                                       \
    }

#define KSTEP(K, SL, PN)                                                         \
    {                                                                            \
        asm volatile("s_waitcnt vmcnt(22)" ::: "memory");                        \
        s16x8 af;                                                                \
        _Pragma("unroll")                                                        \
        for (int e = 0; e < 4; ++e) {                                            \
            float x = (si + gt0[K][e]) * gm0[K][e];                              \
            x = fmaxf(x, 0.2f * x);                                              \
            float p = __expf(x) * ga0[K][e];        /* adj is exactly 0/1 */     \
            lsum += p;                                                           \
            af[e] = (short)f2bf(p);                                              \
        }                                                                        \
        _Pragma("unroll")                                                        \
        for (int e = 0; e < 4; ++e) {                                            \
            float x = (si + gt1[K][e]) * gm1[K][e];                              \
            x = fmaxf(x, 0.2f * x);                                              \
            float p = __expf(x) * ga1[K][e];                                     \
            lsum += p;                                                           \
            af[4 + e] = (short)f2bf(p);                                          \
        }                                                                        \
        const char* sb = &slab[SL][0];                                           \
        _Pragma("unroll")                                                        \
        for (int ct = 0; ct < 8; ++ct) {                                         \
            s16x8 bf = *(const s16x8*)(sb + (ct * 16 + lrow) * 256 +             \
                                       (((K) * 64 + kgrp * 16) ^ ((lrow & 7) << 4))); \
            acc[ct] = __builtin_amdgcn_mfma_f32_16x16x32_bf16(af, bf, acc[ct], 0, 0, 0); \
        }                                                                        \
        LD_G(K, PN)                                                              \
    }

    // prologue: DMA(stage0) [4] + groups k0..3 [24]; retire DMA; barrier
    DMA_HT(PH, 0)
    LD_G(0, PH)
    LD_G(1, PH)
    LD_G(2, PH)
    LD_G(3, PH)
    asm volatile("s_waitcnt vmcnt(24)" ::: "memory");
    __builtin_amdgcn_s_barrier();
    asm volatile("" ::: "memory");

#pragma unroll 1
    for (int s = 0; s < NS; ++s) {
        const int pn = (s + 1 + PH) & (NS - 1);   // physical next stage (wraps to dup at tail)
        const int sl = s & 1;
        DMA_HT(pn, (s + 1) & 1)
        KSTEP(0, sl, pn)
        KSTEP(1, sl, pn)
        KSTEP(2, sl, pn)
        KSTEP(3, sl, pn)
        asm volatile("s_waitcnt vmcnt(24)" ::: "memory");  // next-slab DMA retired (all waves)
        __builtin_amdgcn_s_barrier();
        asm volatile("" ::: "memory");
    }
#undef DMA_HT
#undef LD_G
#undef KSTEP

    // denominator partials: lanes {l, l^16, l^32, l^48} share row lrow
    lsum += __shfl_xor(lsum, 16);
    lsum += __shfl_xor(lsum, 32);
    if (l < 16) l_part[(size_t)jc * NN + i] = lsum;

    // o partials (D layout: row=(lane>>4)*4+reg, col=lane&15)
    float* op = o_part + (size_t)jc * NN * KOUT;
#pragma unroll
    for (int ct = 0; ct < 8; ++ct) {
#pragma unroll
        for (int r = 0; r < 4; ++r) {
            int gi = row0 + w * 16 + kgrp * 4 + r;
            int col = ct * 16 + lrow;
            op[(size_t)gi * KOUT + col] = acc[ct][r];
        }
    }
}

// ---------------- Kernel C: reduce partials, divide, ELU ----------------
__global__ __launch_bounds__(256) void kC(const float* __restrict__ o_part,
                                          const float* __restrict__ l_part,
                                          float* __restrict__ out) {
    const int idx = blockIdx.x * 256 + threadIdx.x;
    const int i = idx >> 7;
    float osum = 0.f, lsum = 0.f;
#pragma unroll
    for (int p = 0; p < JC; ++p) {
        osum += o_part[(size_t)p * NN * KOUT + idx];
        lsum += l_part[(size_t)p * NN + i];
    }
    float v = osum / lsum;
    out[idx] = v > 0.f ? v : (__expf(v) - 1.f);
}

extern "C" void kernel_launch(void* const* d_in, const int* in_sizes, int n_in,
                              void* d_out, int out_size, void* d_ws, size_t ws_size,
                              hipStream_t stream) {
    const float* inp = (const float*)d_in[0];
    const float* adj = (const float*)d_in[1];
    const float* Mm  = (const float*)d_in[2];
    const float* W   = (const float*)d_in[3];
    const float* a_s = (const float*)d_in[4];
    const float* a_n = (const float*)d_in[5];
    float* out = (float*)d_out;

    char* ws = (char*)d_ws;
    ushort* hT    = (ushort*)(ws + 0);              //  2 MB   [128][8192] bf16
    float*  s_buf = (float*)(ws + 2097152);         //  32 KB
    float*  t_buf = (float*)(ws + 2129920);         //  32 KB
    float*  l_prt = (float*)(ws + 2162688);         //  128 KB [4][8192]
    float*  o_prt = (float*)(ws + 4194304);         //  16 MB  [4][8192][128]

    hipLaunchKernelGGL(kA, dim3(512), dim3(256), 0, stream, inp, W, a_s, a_n, hT, s_buf, t_buf);
    hipLaunchKernelGGL(kG, dim3(64 * JC), dim3(512), 0, stream, Mm, adj, hT, s_buf, t_buf, o_prt, l_prt);
    hipLaunchKernelGGL(kC, dim3(4096), dim3(256), 0, stream, o_prt, l_prt, out);
}